// Round 8
// baseline (211.842 us; speedup 1.0000x reference)
//
#include <hip/hip_runtime.h>
#include <hip/hip_bf16.h>

typedef __hip_bfloat16 bf16;
typedef __attribute__((ext_vector_type(8))) short bf16x8;
typedef __attribute__((ext_vector_type(4))) short bf16x4;
typedef __attribute__((ext_vector_type(4))) float f32x4;

static constexpr int B_ = 4, S_ = 2048, E_ = 1024, H_ = 16, D_ = 64;
static constexpr int M_ = B_ * S_;   // 8192
static constexpr int NQKV = 3 * E_;  // 3072

__device__ __forceinline__ void gload_lds16(const void* g, void* l) {
  __builtin_amdgcn_global_load_lds(
      (const __attribute__((address_space(1))) unsigned int*)g,
      (__attribute__((address_space(3))) unsigned int*)l, 16, 0, 0);
}

__device__ __forceinline__ void cast8(const float* __restrict__ src,
                                      bf16* __restrict__ dst, int t) {
  float4 a = ((const float4*)src)[2 * t];
  float4 b = ((const float4*)src)[2 * t + 1];
  union { bf16x8 v; bf16 e[8]; } u;
  u.e[0] = __float2bfloat16(a.x); u.e[1] = __float2bfloat16(a.y);
  u.e[2] = __float2bfloat16(a.z); u.e[3] = __float2bfloat16(a.w);
  u.e[4] = __float2bfloat16(b.x); u.e[5] = __float2bfloat16(b.y);
  u.e[6] = __float2bfloat16(b.z); u.e[7] = __float2bfloat16(b.w);
  ((bf16x8*)dst)[t] = u.v;
}

// ---------- fused prologue: casts + rope tables, one launch ----------
__global__ void prep_kernel(const float* __restrict__ x, const float* __restrict__ Wq,
                            const float* __restrict__ Wk, const float* __restrict__ Wv,
                            const float* __restrict__ Wp,
                            bf16* __restrict__ x_bf, bf16* __restrict__ w_bf,
                            float2* __restrict__ qtab, float2* __restrict__ ktab) {
  int bid = blockIdx.x;
  if (bid < 4096) {
    cast8(x, x_bf, bid * 256 + threadIdx.x);
  } else if (bid < 6144) {
    int wi = (bid - 4096) >> 9;
    const float* src = wi == 0 ? Wq : wi == 1 ? Wk : wi == 2 ? Wv : Wp;
    cast8(src, w_bf + (size_t)wi * E_ * E_, ((bid - 4096) & 511) * 256 + threadIdx.x);
  } else {
    int tt = (bid - 6144) * 256 + threadIdx.x;  // < S_*32
    int i = tt & 31, s = tt >> 5;
    float inv_freq = powf(10000.0f, -(float)i / 32.0f);
    float ang = (float)s * inv_freq;
    float c = cosf(ang), sn = sinf(ang);
    const float qsc = 0.18033688011112043f;  // 1/8 * log2(e)
    qtab[tt] = make_float2(c * qsc, sn * qsc);
    ktab[tt] = make_float2(c, sn);
  }
}

// ---------- 256x256 8-phase GEMM: C[m][n] = sum_k A[m][k] * Bw[n][k] ----------
// 512 thr = 8 waves (2M x 4N), per-wave 128x64 out; BK=64; double-buffered
// 128 KB LDS; per-phase {ds-read subtile | 1-2 half-tile stages -> barrier ->
// lgkmcnt(0) -> setprio+16 MFMA -> barrier}; vmcnt(4) only at ph4/ph8.
// Half-tile = the rows read by one quadrant phase (A: {0-63,128-191} etc).
// Source-side XOR chunk swizzle (chunk ^= row&7) -> conflict-free ds_read_b128.
// OUTMODE 1: f32 out + bias. OUTMODE 2: fused QKV rope/layout epilogue.
template <int OUTMODE>
__launch_bounds__(512, 2)
__global__ void gemm_bt_kernel(const bf16* __restrict__ A, int lda,
                               const bf16* __restrict__ Bw, int ldb,
                               void* __restrict__ Cv, int ldc,
                               const float* __restrict__ bias,
                               int K, int ntiles_n,
                               const float2* __restrict__ qtab,
                               const float2* __restrict__ ktab,
                               bf16* __restrict__ qh,
                               bf16* __restrict__ khsw,
                               bf16* __restrict__ vtsw) {
  __shared__ bf16 Asm[2][256 * 64];
  __shared__ bf16 Bsm[2][256 * 64];
  int t = threadIdx.x;
  int lane = t & 63, wid = t >> 6;
  int wm = wid >> 2, wn = wid & 3;
  int l15 = lane & 15, l4 = lane >> 4;
  int l8 = lane >> 3, c8 = lane & 7;
  int csw = (c8 ^ l8) * 8;  // swizzled source chunk (elem offset)

  // XCD-aware bijective swizzle (gridDim.x % 8 == 0 by construction)
  int cpx = gridDim.x >> 3;
  int swb = (blockIdx.x & 7) * cpx + (blockIdx.x >> 3);
  int n0 = (swb % ntiles_n) * 256;
  int m0 = (swb / ntiles_n) * 256;

// stage one A half-tile (rows {mh*64..+63} of each 128-row group) of k-tile kt
#define STAGE_A(sb, kt, mh)                                                    \
  do {                                                                         \
    _Pragma("unroll") for (int i_ = 0; i_ < 2; i_++) {                         \
      int lrb = i_ * 128 + (mh) * 64 + wid * 8;                                \
      gload_lds16(A + (size_t)(m0 + lrb + l8) * lda + (kt) * 64 + csw,         \
                  &Asm[sb][lrb * 64]);                                         \
    }                                                                          \
  } while (0)

// stage one B half-tile (rows {nh*32..+31} of each 64-row group) of k-tile kt
#define STAGE_B(sb, kt, nh)                                                    \
  do {                                                                         \
    _Pragma("unroll") for (int i_ = 0; i_ < 2; i_++) {                         \
      int hb = i_ * 64 + wid * 8;                                              \
      int nrb = (hb >> 5) * 64 + (nh) * 32 + (hb & 31);                        \
      gload_lds16(Bw + (size_t)(n0 + nrb + l8) * ldb + (kt) * 64 + csw,        \
                  &Bsm[sb][nrb * 64]);                                         \
    }                                                                          \
  } while (0)

#define LDA(cbuf, mh)                                                          \
  do {                                                                         \
    _Pragma("unroll") for (int i_ = 0; i_ < 4; i_++) {                         \
      int ra = wm * 128 + (mh) * 64 + i_ * 16 + l15;                           \
      int rs = (ra & 7) * 8;                                                   \
      am[i_][0] = *(const bf16x8*)&Asm[cbuf][ra * 64 + ((l4 * 8) ^ rs)];       \
      am[i_][1] = *(const bf16x8*)&Asm[cbuf][ra * 64 + ((32 + l4 * 8) ^ rs)];  \
    }                                                                          \
  } while (0)

#define LDB(cbuf, nh)                                                          \
  do {                                                                         \
    _Pragma("unroll") for (int j_ = 0; j_ < 2; j_++) {                         \
      int rb = wn * 64 + (nh) * 32 + j_ * 16 + l15;                            \
      int rs = (rb & 7) * 8;                                                   \
      bn[nh][j_][0] = *(const bf16x8*)&Bsm[cbuf][rb * 64 + ((l4 * 8) ^ rs)];   \
      bn[nh][j_][1] = *(const bf16x8*)&Bsm[cbuf][rb * 64 + ((32 + l4 * 8) ^ rs)]; \
    }                                                                          \
  } while (0)

#define QUAD(mh, nh)                                                           \
  do {                                                                         \
    __builtin_amdgcn_s_setprio(1);                                             \
    _Pragma("unroll") for (int kk_ = 0; kk_ < 2; kk_++)                        \
      _Pragma("unroll") for (int i_ = 0; i_ < 4; i_++)                         \
        _Pragma("unroll") for (int j_ = 0; j_ < 2; j_++)                       \
          acc[(mh) * 4 + i_][(nh) * 2 + j_] =                                  \
              __builtin_amdgcn_mfma_f32_16x16x32_bf16(                         \
                  am[i_][kk_], bn[nh][j_][kk_],                                \
                  acc[(mh) * 4 + i_][(nh) * 2 + j_], 0, 0, 0);                 \
    __builtin_amdgcn_s_setprio(0);                                             \
  } while (0)

#define PH_SYNC_R                                                              \
  __builtin_amdgcn_s_barrier();                                                \
  asm volatile("s_waitcnt lgkmcnt(0)" ::: "memory");                           \
  __builtin_amdgcn_sched_barrier(0)

  f32x4 acc[8][4];
#pragma unroll
  for (int i = 0; i < 8; i++)
#pragma unroll
    for (int j = 0; j < 4; j++) acc[i][j] = (f32x4){0.f, 0.f, 0.f, 0.f};
  bf16x8 am[4][2];
  bf16x8 bn[2][2][2];

  int NI = K >> 7;  // K/128 double-K-tile iterations
  // prologue: tile0 (A,B) + tile1 (A); vmcnt(4) -> tile0 landed
  STAGE_A(0, 0, 0); STAGE_A(0, 0, 1); STAGE_B(0, 0, 0); STAGE_B(0, 0, 1);
  STAGE_A(1, 1, 0); STAGE_A(1, 1, 1);
  asm volatile("s_waitcnt vmcnt(4)" ::: "memory");
  __builtin_amdgcn_s_barrier();

  for (int it = 0; it < NI; it++) {
    int T = 2 * it;
    bool more = (it + 1 < NI);
    // ph1: quadrant (0,0) of tile T; stage B halves of tile T+1
    LDA(0, 0); LDB(0, 0);
    STAGE_B(1, T + 1, 0); STAGE_B(1, T + 1, 1);
    PH_SYNC_R;
    QUAD(0, 0);
    __builtin_amdgcn_s_barrier();
    // ph2: quadrant (0,1); stage A0(T+2)
    LDB(0, 1);
    if (more) STAGE_A(0, T + 2, 0);
    PH_SYNC_R;
    QUAD(0, 1);
    __builtin_amdgcn_s_barrier();
    // ph3: quadrant (1,0)
    LDA(0, 1);
    PH_SYNC_R;
    QUAD(1, 0);
    __builtin_amdgcn_s_barrier();
    // ph4: quadrant (1,1); stage A1(T+2); counted vmcnt -> tile T+1 landed
    if (more) STAGE_A(0, T + 2, 1);
    __builtin_amdgcn_s_barrier();
    QUAD(1, 1);
    if (more) asm volatile("s_waitcnt vmcnt(4)" ::: "memory");
    else      asm volatile("s_waitcnt vmcnt(0)" ::: "memory");
    __builtin_amdgcn_s_barrier();
    // ph5: tile T+1 quadrant (0,0); stage B0(T+2)
    LDA(1, 0); LDB(1, 0);
    if (more) STAGE_B(0, T + 2, 0);
    PH_SYNC_R;
    QUAD(0, 0);
    __builtin_amdgcn_s_barrier();
    // ph6: quadrant (0,1); stage B1(T+2)
    LDB(1, 1);
    if (more) STAGE_B(0, T + 2, 1);
    PH_SYNC_R;
    QUAD(0, 1);
    __builtin_amdgcn_s_barrier();
    // ph7: quadrant (1,0); stage A0(T+3)
    LDA(1, 1);
    if (more) STAGE_A(1, T + 3, 0);
    PH_SYNC_R;
    QUAD(1, 0);
    __builtin_amdgcn_s_barrier();
    // ph8: quadrant (1,1); stage A1(T+3); counted vmcnt -> tile T+2 landed
    if (more) STAGE_A(1, T + 3, 1);
    __builtin_amdgcn_s_barrier();
    QUAD(1, 1);
    if (more) asm volatile("s_waitcnt vmcnt(4)" ::: "memory");
    __builtin_amdgcn_s_barrier();
  }
#undef STAGE_A
#undef STAGE_B
#undef LDA
#undef LDB
#undef QUAD
#undef PH_SYNC_R

  if (OUTMODE == 1) {
#pragma unroll
    for (int mi = 0; mi < 8; mi++)
#pragma unroll
      for (int j = 0; j < 4; j++)
#pragma unroll
        for (int r = 0; r < 4; r++) {
          int m = m0 + wm * 128 + mi * 16 + l4 * 4 + r;
          int n = n0 + wn * 64 + j * 16 + l15;
          ((float*)Cv)[(size_t)m * ldc + n] = acc[mi][j][r] + bias[n];
        }
  } else {
    int btype = n0 >> 10;                 // 0=Q, 1=K, 2=V (BN=256 never straddles)
    int h = ((n0 & 1023) >> 6) + wn;      // each wave owns one full head (64 cols)
    if (btype < 2) {
      const float2* tab = (btype == 0) ? qtab : ktab;
#pragma unroll
      for (int mi = 0; mi < 8; mi++) {
        int mbase = m0 + wm * 128 + mi * 16 + l4 * 4;
#pragma unroll
        for (int r = 0; r < 4; r++) {
          int m = mbase + r;
          int s = m & 2047, b = m >> 11;
#pragma unroll
          for (int j = 0; j < 2; j++) {
            int d1 = j * 16 + l15;
            float2 cs = tab[s * 32 + d1];
            float t1 = acc[mi][j][r], t2 = acc[mi][j + 2][r];
            bf16 o1 = __float2bfloat16(t1 * cs.x - t2 * cs.y);
            bf16 o2 = __float2bfloat16(t1 * cs.y + t2 * cs.x);
            if (btype == 0) {
              bf16* dst = qh + ((size_t)(b * H_ + h) * S_ + s) * D_;
              dst[d1] = o1;
              dst[d1 + 32] = o2;
            } else {
              int row = s & 63, kt = s >> 6, sz = (row & 7) * 8;
              bf16* dst = khsw + (((size_t)(b * H_ + h) * 32 + kt) * 64 + row) * 64;
              dst[d1 ^ sz] = o1;
              dst[(d1 + 32) ^ sz] = o2;
            }
          }
        }
      }
    } else {
#pragma unroll
      for (int mi = 0; mi < 8; mi++) {
        int mbase = m0 + wm * 128 + mi * 16 + l4 * 4;
        int c0 = mbase & 63, kt = (mbase >> 6) & 31, b = mbase >> 11;
#pragma unroll
        for (int j = 0; j < 4; j++) {
          int d = j * 16 + l15;
          union { bf16x4 v; short e[4]; } pk;
#pragma unroll
          for (int r = 0; r < 4; r++) {
            bf16 tv = __float2bfloat16(acc[mi][j][r]);
            pk.e[r] = *(short*)&tv;
          }
          *(bf16x4*)&vtsw[(((size_t)(b * H_ + h) * 32 + kt) * 64 + d) * 64 +
                          (c0 ^ ((d & 7) * 8))] = pk.v;
        }
      }
    }
  }
}

// ---------- Flash attention: S^T QK (lane-local softmax) + K=32 PV ----------
__launch_bounds__(256, 3)
__global__ void attn_kernel(const bf16* __restrict__ qh, const bf16* __restrict__ khsw,
                            const bf16* __restrict__ vtsw, bf16* __restrict__ attn) {
  __shared__ bf16 Ksm[2][4096];
  __shared__ bf16 Vsm[2][4096];
  __shared__ bf16 Plds[4][2][16][72];
  int t = threadIdx.x, lane = t & 63, w = t >> 6;
  int l15 = lane & 15, l4 = lane >> 4;
  int swz = (l15 & 7) * 8;
  int st = 15 - (blockIdx.x >> 6);   // heavy strips dispatched first
  int bh = blockIdx.x & 63;
  int b = bh >> 4, h = bh & 15;
  const bf16* Qh = qh + (size_t)bh * S_ * D_;

#define STAGE(bb, kt)                                                          \
  do {                                                                         \
    const bf16* kb_ = khsw + ((size_t)bh * 32 + (kt)) * 4096 + w * 1024 + lane * 8; \
    const bf16* vb_ = vtsw + ((size_t)bh * 32 + (kt)) * 4096 + w * 1024 + lane * 8; \
    gload_lds16(kb_, &Ksm[bb][w * 1024]);                                      \
    gload_lds16(kb_ + 512, &Ksm[bb][w * 1024 + 512]);                          \
    gload_lds16(vb_, &Vsm[bb][w * 1024]);                                      \
    gload_lds16(vb_ + 512, &Vsm[bb][w * 1024 + 512]);                          \
  } while (0)

  int q0 = st * 128 + w * 32;
  int nt = 2 * st + 2;

  bf16x8 qf[2][2];
#pragma unroll
  for (int qg = 0; qg < 2; qg++)
#pragma unroll
    for (int sl = 0; sl < 2; sl++)
      qf[qg][sl] = *(const bf16x8*)&Qh[(size_t)(q0 + qg * 16 + l15) * D_ + sl * 32 + l4 * 8];

  f32x4 acc_o[2][4];
  float lsum[2] = {0.f, 0.f};
#pragma unroll
  for (int qg = 0; qg < 2; qg++)
#pragma unroll
    for (int j = 0; j < 4; j++) acc_o[qg][j] = (f32x4){0.f, 0.f, 0.f, 0.f};

  STAGE(0, 0);
  __syncthreads();
  int buf = 0;
  for (int ti = 0; ti < nt; ti++) {
    int kb = ti * 64;
    if (ti + 1 < nt) STAGE(buf ^ 1, ti + 1);
    if (kb <= q0 + 31) {
      bool maskt = (kb + 63 > q0);
      // S^T[key][q] = mfma(A=K, B=Q); Q pre-scaled by 1/sqrt(D)*log2(e)
      f32x4 s[2][4];
      __builtin_amdgcn_s_setprio(1);
#pragma unroll
      for (int cb = 0; cb < 4; cb++) {
        bf16x8 kf0 = *(const bf16x8*)&Ksm[buf][(cb * 16 + l15) * 64 + ((l4 * 8) ^ swz)];
        bf16x8 kf1 = *(const bf16x8*)&Ksm[buf][(cb * 16 + l15) * 64 + ((32 + l4 * 8) ^ swz)];
#pragma unroll
        for (int qg = 0; qg < 2; qg++) {
          f32x4 z = (f32x4){0.f, 0.f, 0.f, 0.f};
          z = __builtin_amdgcn_mfma_f32_16x16x32_bf16(kf0, qf[qg][0], z, 0, 0, 0);
          z = __builtin_amdgcn_mfma_f32_16x16x32_bf16(kf1, qf[qg][1], z, 0, 0, 0);
          s[qg][cb] = z;
        }
      }
      __builtin_amdgcn_s_setprio(0);
      // exp + mask + lsum, all lane-local; pack 4 bf16 -> one ds_write_b64
#pragma unroll
      for (int qg = 0; qg < 2; qg++) {
        int q = q0 + qg * 16 + l15;
#pragma unroll
        for (int cb = 0; cb < 4; cb++) {
          union { bf16x4 v; short e[4]; } pk;
#pragma unroll
          for (int r = 0; r < 4; r++) {
            float p = exp2f(s[qg][cb][r]);
            if (maskt && (kb + cb * 16 + l4 * 4 + r > q)) p = 0.f;
            lsum[qg] += p;
            bf16 pb16 = __float2bfloat16(p);
            pk.e[r] = *(short*)&pb16;
          }
          *(bf16x4*)&Plds[w][qg][l15][cb * 16 + l4 * 4] = pk.v;
        }
      }
      // PV: O += P·V^T with 16x16x32 MFMAs (A=P from Plds, B=V^T from Vsm)
      __builtin_amdgcn_s_setprio(1);
#pragma unroll
      for (int qg = 0; qg < 2; qg++) {
        bf16x8 pf0 = *(const bf16x8*)&Plds[w][qg][l15][l4 * 8];
        bf16x8 pf1 = *(const bf16x8*)&Plds[w][qg][l15][32 + l4 * 8];
#pragma unroll
        for (int db = 0; db < 4; db++) {
          bf16x8 vf0 = *(const bf16x8*)&Vsm[buf][(db * 16 + l15) * 64 + ((l4 * 8) ^ swz)];
          bf16x8 vf1 = *(const bf16x8*)&Vsm[buf][(db * 16 + l15) * 64 + ((32 + l4 * 8) ^ swz)];
          acc_o[qg][db] = __builtin_amdgcn_mfma_f32_16x16x32_bf16(pf0, vf0, acc_o[qg][db], 0, 0, 0);
          acc_o[qg][db] = __builtin_amdgcn_mfma_f32_16x16x32_bf16(pf1, vf1, acc_o[qg][db], 0, 0, 0);
        }
      }
      __builtin_amdgcn_s_setprio(0);
    }
    __syncthreads();
    buf ^= 1;
  }

  // lsum lives per q=l15 (summed over r,cb in-lane); reduce across l4 groups
  float invr[2][4];
#pragma unroll
  for (int qg = 0; qg < 2; qg++) {
    float ls = lsum[qg];
    ls += __shfl_xor(ls, 16, 64);
    ls += __shfl_xor(ls, 32, 64);
    float inv = 1.0f / ls;
#pragma unroll
    for (int r = 0; r < 4; r++) invr[qg][r] = __shfl(inv, l4 * 4 + r, 64);
  }

#pragma unroll
  for (int qg = 0; qg < 2; qg++)
#pragma unroll
    for (int db = 0; db < 4; db++)
#pragma unroll
      for (int r = 0; r < 4; r++) {
        int qa = q0 + qg * 16 + l4 * 4 + r;
        attn[(size_t)(b * S_ + qa) * E_ + h * 64 + db * 16 + l15] =
            __float2bfloat16(acc_o[qg][db][r] * invr[qg][r]);
      }
#undef STAGE
}

extern "C" void kernel_launch(void* const* d_in, const int* in_sizes, int n_in,
                              void* d_out, int out_size, void* d_ws, size_t ws_size,
                              hipStream_t stream) {
  const float* x  = (const float*)d_in[0];
  const float* Wq = (const float*)d_in[1];
  const float* Wk = (const float*)d_in[2];
  const float* Wv = (const float*)d_in[3];
  const float* Wp = (const float*)d_in[4];
  const float* bp = (const float*)d_in[5];

  char* ws = (char*)d_ws;
  bf16* x_bf   = (bf16*)(ws + 0);                     // 16 MB
  bf16* w_bf   = (bf16*)(ws + (16u << 20));           //  8 MB (Wq|Wk|Wv|Wp)
  bf16* aout   = (bf16*)(ws + (24u << 20));           // 16 MB
  bf16* qh     = (bf16*)(ws + (40u << 20));           // 16 MB
  bf16* khsw   = (bf16*)(ws + (56u << 20));           // 16 MB (swizzled tiles)
  bf16* vtsw   = (bf16*)(ws + (72u << 20));           // 16 MB (swizzled tiles)
  float2* qtab = (float2*)(ws + (88u << 20));         // 512 KB
  float2* ktab = (float2*)(ws + (88u << 20) + (512u << 10));  // 512 KB

  prep_kernel<<<6400, 256, 0, stream>>>(x, Wq, Wk, Wv, Wp, x_bf, w_bf, qtab, ktab);

  // fused QKV projection + rope + layout (256x256 tiles: 32 x 12 = 384 blocks)
  gemm_bt_kernel<2><<<(M_ / 256) * (NQKV / 256), 512, 0, stream>>>(
      x_bf, E_, w_bf, E_, nullptr, 0, nullptr, E_, NQKV / 256,
      qtab, ktab, qh, khsw, vtsw);

  attn_kernel<<<16 * 64, 256, 0, stream>>>(qh, khsw, vtsw, aout);

  // output projection + bias (32 x 4 = 128 blocks)
  gemm_bt_kernel<1><<<(M_ / 256) * (E_ / 256), 512, 0, stream>>>(
      aout, E_, w_bf + 3 * (size_t)E_ * E_, E_, d_out, E_, bp, E_, E_ / 256,
      nullptr, nullptr, nullptr, nullptr, nullptr);
}

// Round 9
// 188.734 us; speedup vs baseline: 1.1224x; 1.1224x over previous
//
#include <hip/hip_runtime.h>
#include <hip/hip_bf16.h>

typedef __hip_bfloat16 bf16;
typedef __attribute__((ext_vector_type(8))) short bf16x8;
typedef __attribute__((ext_vector_type(4))) short bf16x4;
typedef __attribute__((ext_vector_type(4))) float f32x4;

static constexpr int B_ = 4, S_ = 2048, E_ = 1024, H_ = 16, D_ = 64;
static constexpr int M_ = B_ * S_;   // 8192
static constexpr int NQKV = 3 * E_;  // 3072

__device__ __forceinline__ void gload_lds16(const void* g, void* l) {
  __builtin_amdgcn_global_load_lds(
      (const __attribute__((address_space(1))) unsigned int*)g,
      (__attribute__((address_space(3))) unsigned int*)l, 16, 0, 0);
}

__device__ __forceinline__ void cast8(const float* __restrict__ src,
                                      bf16* __restrict__ dst, int t) {
  float4 a = ((const float4*)src)[2 * t];
  float4 b = ((const float4*)src)[2 * t + 1];
  union { bf16x8 v; bf16 e[8]; } u;
  u.e[0] = __float2bfloat16(a.x); u.e[1] = __float2bfloat16(a.y);
  u.e[2] = __float2bfloat16(a.z); u.e[3] = __float2bfloat16(a.w);
  u.e[4] = __float2bfloat16(b.x); u.e[5] = __float2bfloat16(b.y);
  u.e[6] = __float2bfloat16(b.z); u.e[7] = __float2bfloat16(b.w);
  ((bf16x8*)dst)[t] = u.v;
}

// ---------- fused prologue: casts + rope tables, one launch ----------
__global__ void prep_kernel(const float* __restrict__ x, const float* __restrict__ Wq,
                            const float* __restrict__ Wk, const float* __restrict__ Wv,
                            const float* __restrict__ Wp,
                            bf16* __restrict__ x_bf, bf16* __restrict__ w_bf,
                            float2* __restrict__ qtab, float2* __restrict__ ktab) {
  int bid = blockIdx.x;
  if (bid < 4096) {
    cast8(x, x_bf, bid * 256 + threadIdx.x);
  } else if (bid < 6144) {
    int wi = (bid - 4096) >> 9;
    const float* src = wi == 0 ? Wq : wi == 1 ? Wk : wi == 2 ? Wv : Wp;
    cast8(src, w_bf + (size_t)wi * E_ * E_, ((bid - 4096) & 511) * 256 + threadIdx.x);
  } else {
    int tt = (bid - 6144) * 256 + threadIdx.x;  // < S_*32
    int i = tt & 31, s = tt >> 5;
    float inv_freq = powf(10000.0f, -(float)i / 32.0f);
    float ang = (float)s * inv_freq;
    float c = cosf(ang), sn = sinf(ang);
    const float qsc = 0.18033688011112043f;  // 1/8 * log2(e)
    qtab[tt] = make_float2(c * qsc, sn * qsc);
    ktab[tt] = make_float2(c, sn);
  }
}

// ---------- GEMM: C[m][n] = sum_k A[m][k] * Bw[n][k], BK=64, dbuf prefetch ----------
// 128x128 tile, 4 waves, BK=64. Double-buffered LDS (64 KB, 2 blocks/CU):
// STAGE(t+1) issued BEFORE compute(t) (T3-minimum 2-phase), ONE barrier per
// K-step (its implicit vmcnt(0) drain = tile t+1 landed; all waves done
// reading tile t). Source-side XOR chunk swizzle -> conflict-free ds_read_b128.
// OUTMODE 1: f32 out + bias (proj). OUTMODE 2: fused QKV rope/layout epilogue.
template <int OUTMODE>
__launch_bounds__(256)
__global__ void gemm_bt_kernel(const bf16* __restrict__ A, int lda,
                               const bf16* __restrict__ Bw, int ldb,
                               void* __restrict__ Cv, int ldc,
                               const float* __restrict__ bias,
                               int K, int ntiles_n,
                               const float2* __restrict__ qtab,
                               const float2* __restrict__ ktab,
                               bf16* __restrict__ qh,
                               bf16* __restrict__ khsw,
                               bf16* __restrict__ vtsw) {
  __shared__ bf16 Asm[2][128 * 64];
  __shared__ bf16 Bsm[2][128 * 64];
  int t = threadIdx.x;
  int lane = t & 63, w = t >> 6;
  int wr = w >> 1, wc = w & 1;
  int l15 = lane & 15, l4 = lane >> 4;
  int n0 = (blockIdx.x % ntiles_n) * 128;
  int m0 = (blockIdx.x / ntiles_n) * 128;

  // staging: chunk c = p*256 + t; row = c>>3, kg = (c&7) ^ (row&7) (swizzled src)
  int trow = t >> 3;
  int tkg = ((t & 7) ^ (trow & 7)) * 8;
  const bf16* Abase = A + (size_t)(m0 + trow) * lda + tkg;
  const bf16* Bbase = Bw + (size_t)(n0 + trow) * ldb + tkg;

#define GSTAGE(sb, kt)                                                         \
  do {                                                                         \
    const bf16* as_ = Abase + (size_t)(kt) * 64;                               \
    const bf16* bs_ = Bbase + (size_t)(kt) * 64;                               \
    _Pragma("unroll") for (int p = 0; p < 4; p++) {                            \
      gload_lds16(as_ + (size_t)p * 32 * lda, &Asm[sb][(p * 256 + t) * 8]);    \
      gload_lds16(bs_ + (size_t)p * 32 * ldb, &Bsm[sb][(p * 256 + t) * 8]);    \
    }                                                                          \
  } while (0)

  f32x4 acc[4][4];
#pragma unroll
  for (int i = 0; i < 4; i++)
#pragma unroll
    for (int j = 0; j < 4; j++) acc[i][j] = (f32x4){0.f, 0.f, 0.f, 0.f};

  int NT = K >> 6;
  GSTAGE(0, 0);
  __syncthreads();
  int buf = 0;
  for (int ti = 0; ti < NT; ti++) {
    if (ti + 1 < NT) GSTAGE(buf ^ 1, ti + 1);
#pragma unroll
    for (int kk = 0; kk < 2; kk++) {
      bf16x8 am[4], bn[4];
#pragma unroll
      for (int i = 0; i < 4; i++) {
        int ra = wr * 64 + i * 16 + l15;
        am[i] = *(const bf16x8*)&Asm[buf][ra * 64 + ((kk * 32 + l4 * 8) ^ ((ra & 7) * 8))];
        int rb = wc * 64 + i * 16 + l15;
        bn[i] = *(const bf16x8*)&Bsm[buf][rb * 64 + ((kk * 32 + l4 * 8) ^ ((rb & 7) * 8))];
      }
#pragma unroll
      for (int i = 0; i < 4; i++)
#pragma unroll
        for (int j = 0; j < 4; j++)
          acc[i][j] = __builtin_amdgcn_mfma_f32_16x16x32_bf16(am[i], bn[j], acc[i][j], 0, 0, 0);
    }
    __syncthreads();
    buf ^= 1;
  }
#undef GSTAGE

  if (OUTMODE == 1) {
#pragma unroll
    for (int i = 0; i < 4; i++)
#pragma unroll
      for (int j = 0; j < 4; j++)
#pragma unroll
        for (int r = 0; r < 4; r++) {
          int m = m0 + wr * 64 + i * 16 + l4 * 4 + r;
          int n = n0 + wc * 64 + j * 16 + l15;
          ((float*)Cv)[(size_t)m * ldc + n] = acc[i][j][r] + bias[n];
        }
  } else {
    int btype = n0 >> 10;                     // 0=Q, 1=K, 2=V
    int h = ((n0 & 1023) >> 6) + wc;          // head index
    if (btype < 2) {
      const float2* tab = (btype == 0) ? qtab : ktab;
#pragma unroll
      for (int i = 0; i < 4; i++) {
        int mbase = m0 + wr * 64 + i * 16 + l4 * 4;
#pragma unroll
        for (int r = 0; r < 4; r++) {
          int m = mbase + r;
          int s = m & 2047, b = m >> 11;
#pragma unroll
          for (int j = 0; j < 2; j++) {
            int d1 = j * 16 + l15;
            float2 cs = tab[s * 32 + d1];
            float t1 = acc[i][j][r], t2 = acc[i][j + 2][r];
            bf16 o1 = __float2bfloat16(t1 * cs.x - t2 * cs.y);
            bf16 o2 = __float2bfloat16(t1 * cs.y + t2 * cs.x);
            if (btype == 0) {
              bf16* dst = qh + ((size_t)(b * H_ + h) * S_ + s) * D_;
              dst[d1] = o1;
              dst[d1 + 32] = o2;
            } else {
              int row = s & 63, kt = s >> 6, sz = (row & 7) * 8;
              bf16* dst = khsw + (((size_t)(b * H_ + h) * 32 + kt) * 64 + row) * 64;
              dst[d1 ^ sz] = o1;
              dst[(d1 + 32) ^ sz] = o2;
            }
          }
        }
      }
    } else {
#pragma unroll
      for (int i = 0; i < 4; i++) {
        int mbase = m0 + wr * 64 + i * 16 + l4 * 4;
        int c0 = mbase & 63, kt = (mbase >> 6) & 31, b = mbase >> 11;
#pragma unroll
        for (int j = 0; j < 4; j++) {
          int d = j * 16 + l15;
          union { bf16x4 v; short e[4]; } pk;
#pragma unroll
          for (int r = 0; r < 4; r++) {
            bf16 tv = __float2bfloat16(acc[i][j][r]);
            pk.e[r] = *(short*)&tv;
          }
          *(bf16x4*)&vtsw[(((size_t)(b * H_ + h) * 32 + kt) * 64 + d) * 64 +
                          (c0 ^ ((d & 7) * 8))] = pk.v;
        }
      }
    }
  }
}

// ---------- Flash attention: S^T QK (lane-local softmax) + K=32 PV ----------
__launch_bounds__(256, 3)
__global__ void attn_kernel(const bf16* __restrict__ qh, const bf16* __restrict__ khsw,
                            const bf16* __restrict__ vtsw, bf16* __restrict__ attn) {
  __shared__ bf16 Ksm[2][4096];
  __shared__ bf16 Vsm[2][4096];
  __shared__ bf16 Plds[4][2][16][72];
  int t = threadIdx.x, lane = t & 63, w = t >> 6;
  int l15 = lane & 15, l4 = lane >> 4;
  int swz = (l15 & 7) * 8;
  int st = 15 - (blockIdx.x >> 6);   // heavy strips dispatched first
  int bh = blockIdx.x & 63;
  int b = bh >> 4, h = bh & 15;
  const bf16* Qh = qh + (size_t)bh * S_ * D_;

#define STAGE(bb, kt)                                                          \
  do {                                                                         \
    const bf16* kb_ = khsw + ((size_t)bh * 32 + (kt)) * 4096 + w * 1024 + lane * 8; \
    const bf16* vb_ = vtsw + ((size_t)bh * 32 + (kt)) * 4096 + w * 1024 + lane * 8; \
    gload_lds16(kb_, &Ksm[bb][w * 1024]);                                      \
    gload_lds16(kb_ + 512, &Ksm[bb][w * 1024 + 512]);                          \
    gload_lds16(vb_, &Vsm[bb][w * 1024]);                                      \
    gload_lds16(vb_ + 512, &Vsm[bb][w * 1024 + 512]);                          \
  } while (0)

  int q0 = st * 128 + w * 32;
  int nt = 2 * st + 2;

  bf16x8 qf[2][2];
#pragma unroll
  for (int qg = 0; qg < 2; qg++)
#pragma unroll
    for (int sl = 0; sl < 2; sl++)
      qf[qg][sl] = *(const bf16x8*)&Qh[(size_t)(q0 + qg * 16 + l15) * D_ + sl * 32 + l4 * 8];

  f32x4 acc_o[2][4];
  float lsum[2] = {0.f, 0.f};
#pragma unroll
  for (int qg = 0; qg < 2; qg++)
#pragma unroll
    for (int j = 0; j < 4; j++) acc_o[qg][j] = (f32x4){0.f, 0.f, 0.f, 0.f};

  STAGE(0, 0);
  __syncthreads();
  int buf = 0;
  for (int ti = 0; ti < nt; ti++) {
    int kb = ti * 64;
    if (ti + 1 < nt) STAGE(buf ^ 1, ti + 1);
    if (kb <= q0 + 31) {
      bool maskt = (kb + 63 > q0);
      // S^T[key][q] = mfma(A=K, B=Q); Q pre-scaled by 1/sqrt(D)*log2(e)
      f32x4 s[2][4];
      __builtin_amdgcn_s_setprio(1);
#pragma unroll
      for (int cb = 0; cb < 4; cb++) {
        bf16x8 kf0 = *(const bf16x8*)&Ksm[buf][(cb * 16 + l15) * 64 + ((l4 * 8) ^ swz)];
        bf16x8 kf1 = *(const bf16x8*)&Ksm[buf][(cb * 16 + l15) * 64 + ((32 + l4 * 8) ^ swz)];
#pragma unroll
        for (int qg = 0; qg < 2; qg++) {
          f32x4 z = (f32x4){0.f, 0.f, 0.f, 0.f};
          z = __builtin_amdgcn_mfma_f32_16x16x32_bf16(kf0, qf[qg][0], z, 0, 0, 0);
          z = __builtin_amdgcn_mfma_f32_16x16x32_bf16(kf1, qf[qg][1], z, 0, 0, 0);
          s[qg][cb] = z;
        }
      }
      __builtin_amdgcn_s_setprio(0);
      // exp + mask + lsum, all lane-local; pack 4 bf16 -> one ds_write_b64
#pragma unroll
      for (int qg = 0; qg < 2; qg++) {
        int q = q0 + qg * 16 + l15;
#pragma unroll
        for (int cb = 0; cb < 4; cb++) {
          union { bf16x4 v; short e[4]; } pk;
#pragma unroll
          for (int r = 0; r < 4; r++) {
            float p = exp2f(s[qg][cb][r]);
            if (maskt && (kb + cb * 16 + l4 * 4 + r > q)) p = 0.f;
            lsum[qg] += p;
            bf16 pb16 = __float2bfloat16(p);
            pk.e[r] = *(short*)&pb16;
          }
          *(bf16x4*)&Plds[w][qg][l15][cb * 16 + l4 * 4] = pk.v;
        }
      }
      // PV: O += P·V^T with 16x16x32 MFMAs (A=P from Plds, B=V^T from Vsm)
      __builtin_amdgcn_s_setprio(1);
#pragma unroll
      for (int qg = 0; qg < 2; qg++) {
        bf16x8 pf0 = *(const bf16x8*)&Plds[w][qg][l15][l4 * 8];
        bf16x8 pf1 = *(const bf16x8*)&Plds[w][qg][l15][32 + l4 * 8];
#pragma unroll
        for (int db = 0; db < 4; db++) {
          bf16x8 vf0 = *(const bf16x8*)&Vsm[buf][(db * 16 + l15) * 64 + ((l4 * 8) ^ swz)];
          bf16x8 vf1 = *(const bf16x8*)&Vsm[buf][(db * 16 + l15) * 64 + ((32 + l4 * 8) ^ swz)];
          acc_o[qg][db] = __builtin_amdgcn_mfma_f32_16x16x32_bf16(pf0, vf0, acc_o[qg][db], 0, 0, 0);
          acc_o[qg][db] = __builtin_amdgcn_mfma_f32_16x16x32_bf16(pf1, vf1, acc_o[qg][db], 0, 0, 0);
        }
      }
      __builtin_amdgcn_s_setprio(0);
    }
    __syncthreads();
    buf ^= 1;
  }

  // lsum lives per q=l15 (summed over r,cb in-lane); reduce across l4 groups
  float invr[2][4];
#pragma unroll
  for (int qg = 0; qg < 2; qg++) {
    float ls = lsum[qg];
    ls += __shfl_xor(ls, 16, 64);
    ls += __shfl_xor(ls, 32, 64);
    float inv = 1.0f / ls;
#pragma unroll
    for (int r = 0; r < 4; r++) invr[qg][r] = __shfl(inv, l4 * 4 + r, 64);
  }

#pragma unroll
  for (int qg = 0; qg < 2; qg++)
#pragma unroll
    for (int db = 0; db < 4; db++)
#pragma unroll
      for (int r = 0; r < 4; r++) {
        int qa = q0 + qg * 16 + l4 * 4 + r;
        attn[(size_t)(b * S_ + qa) * E_ + h * 64 + db * 16 + l15] =
            __float2bfloat16(acc_o[qg][db][r] * invr[qg][r]);
      }
#undef STAGE
}

extern "C" void kernel_launch(void* const* d_in, const int* in_sizes, int n_in,
                              void* d_out, int out_size, void* d_ws, size_t ws_size,
                              hipStream_t stream) {
  const float* x  = (const float*)d_in[0];
  const float* Wq = (const float*)d_in[1];
  const float* Wk = (const float*)d_in[2];
  const float* Wv = (const float*)d_in[3];
  const float* Wp = (const float*)d_in[4];
  const float* bp = (const float*)d_in[5];

  char* ws = (char*)d_ws;
  bf16* x_bf   = (bf16*)(ws + 0);                     // 16 MB
  bf16* w_bf   = (bf16*)(ws + (16u << 20));           //  8 MB (Wq|Wk|Wv|Wp)
  bf16* aout   = (bf16*)(ws + (24u << 20));           // 16 MB
  bf16* qh     = (bf16*)(ws + (40u << 20));           // 16 MB
  bf16* khsw   = (bf16*)(ws + (56u << 20));           // 16 MB (swizzled tiles)
  bf16* vtsw   = (bf16*)(ws + (72u << 20));           // 16 MB (swizzled tiles)
  float2* qtab = (float2*)(ws + (88u << 20));         // 512 KB
  float2* ktab = (float2*)(ws + (88u << 20) + (512u << 10));  // 512 KB

  prep_kernel<<<6400, 256, 0, stream>>>(x, Wq, Wk, Wv, Wp, x_bf, w_bf, qtab, ktab);

  // fused QKV projection + rope + layout (writes qh/khsw/vtsw directly)
  gemm_bt_kernel<2><<<(M_ / 128) * (NQKV / 128), 256, 0, stream>>>(
      x_bf, E_, w_bf, E_, nullptr, 0, nullptr, E_, NQKV / 128,
      qtab, ktab, qh, khsw, vtsw);

  attn_kernel<<<16 * 64, 256, 0, stream>>>(qh, khsw, vtsw, aout);

  gemm_bt_kernel<1><<<(M_ / 128) * (E_ / 128), 256, 0, stream>>>(
      aout, E_, w_bf + 3 * (size_t)E_ * E_, E_, d_out, E_, bp, E_, E_ / 128,
      nullptr, nullptr, nullptr, nullptr, nullptr);
}

// Round 10
// 176.187 us; speedup vs baseline: 1.2024x; 1.0712x over previous
//
#include <hip/hip_runtime.h>
#include <hip/hip_bf16.h>

typedef __hip_bfloat16 bf16;
typedef __attribute__((ext_vector_type(8))) short bf16x8;
typedef __attribute__((ext_vector_type(4))) short bf16x4;
typedef __attribute__((ext_vector_type(4))) float f32x4;

static constexpr int B_ = 4, S_ = 2048, E_ = 1024, H_ = 16, D_ = 64;
static constexpr int M_ = B_ * S_;   // 8192
static constexpr int NQKV = 3 * E_;  // 3072

__device__ __forceinline__ void gload_lds16(const void* g, void* l) {
  __builtin_amdgcn_global_load_lds(
      (const __attribute__((address_space(1))) unsigned int*)g,
      (__attribute__((address_space(3))) unsigned int*)l, 16, 0, 0);
}

__device__ __forceinline__ void cast8(const float* __restrict__ src,
                                      bf16* __restrict__ dst, int t) {
  float4 a = ((const float4*)src)[2 * t];
  float4 b = ((const float4*)src)[2 * t + 1];
  union { bf16x8 v; bf16 e[8]; } u;
  u.e[0] = __float2bfloat16(a.x); u.e[1] = __float2bfloat16(a.y);
  u.e[2] = __float2bfloat16(a.z); u.e[3] = __float2bfloat16(a.w);
  u.e[4] = __float2bfloat16(b.x); u.e[5] = __float2bfloat16(b.y);
  u.e[6] = __float2bfloat16(b.z); u.e[7] = __float2bfloat16(b.w);
  ((bf16x8*)dst)[t] = u.v;
}

// ---------- fused prologue: casts + rope tables, one launch ----------
__global__ void prep_kernel(const float* __restrict__ x, const float* __restrict__ Wq,
                            const float* __restrict__ Wk, const float* __restrict__ Wv,
                            const float* __restrict__ Wp,
                            bf16* __restrict__ x_bf, bf16* __restrict__ w_bf,
                            float2* __restrict__ qtab, float2* __restrict__ ktab) {
  int bid = blockIdx.x;
  if (bid < 4096) {
    cast8(x, x_bf, bid * 256 + threadIdx.x);
  } else if (bid < 6144) {
    int wi = (bid - 4096) >> 9;
    const float* src = wi == 0 ? Wq : wi == 1 ? Wk : wi == 2 ? Wv : Wp;
    cast8(src, w_bf + (size_t)wi * E_ * E_, ((bid - 4096) & 511) * 256 + threadIdx.x);
  } else {
    int tt = (bid - 6144) * 256 + threadIdx.x;  // < S_*32
    int i = tt & 31, s = tt >> 5;
    float inv_freq = powf(10000.0f, -(float)i / 32.0f);
    float ang = (float)s * inv_freq;
    float c = cosf(ang), sn = sinf(ang);
    const float qsc = 0.18033688011112043f;  // 1/8 * log2(e)
    qtab[tt] = make_float2(c * qsc, sn * qsc);
    ktab[tt] = make_float2(c, sn);
  }
}

// ---------- GEMM: C[m][n] = sum_k A[m][k] * Bw[n][k], BK=64, swizzled LDS ----------
// R6-proven structure: 128x128 tile, 4 waves, BK=64, single-buffered 32 KB LDS,
// stage -> barrier(drain) -> compute -> barrier. Source-side XOR chunk swizzle
// (kg ^= row&7) -> conflict-free ds_read_b128. NEW vs R6: T1 XCD-aware
// bijective block swizzle (gridDim.x % 8 == 0) for per-XCD L2 panel reuse.
// OUTMODE 1: f32 out + bias (proj). OUTMODE 2: fused QKV rope/layout epilogue.
template <int OUTMODE>
__launch_bounds__(256)
__global__ void gemm_bt_kernel(const bf16* __restrict__ A, int lda,
                               const bf16* __restrict__ Bw, int ldb,
                               void* __restrict__ Cv, int ldc,
                               const float* __restrict__ bias,
                               int K, int ntiles_n,
                               const float2* __restrict__ qtab,
                               const float2* __restrict__ ktab,
                               bf16* __restrict__ qh,
                               bf16* __restrict__ khsw,
                               bf16* __restrict__ vtsw) {
  __shared__ bf16 Asm[128 * 64];
  __shared__ bf16 Bsm[128 * 64];
  int t = threadIdx.x;
  int lane = t & 63, w = t >> 6;
  int wr = w >> 1, wc = w & 1;
  int l15 = lane & 15, l4 = lane >> 4;

  // T1: XCD-aware bijective swizzle; gridDim.x is a multiple of 8.
  int cpx = gridDim.x >> 3;
  int swb = (blockIdx.x & 7) * cpx + (blockIdx.x >> 3);
  int n0 = (swb % ntiles_n) * 128;
  int m0 = (swb / ntiles_n) * 128;

  f32x4 acc[4][4];
#pragma unroll
  for (int i = 0; i < 4; i++)
#pragma unroll
    for (int j = 0; j < 4; j++) acc[i][j] = (f32x4){0.f, 0.f, 0.f, 0.f};

  for (int k0 = 0; k0 < K; k0 += 64) {
#pragma unroll
    for (int p = 0; p < 4; p++) {
      int c = p * 256 + t;
      int row = c >> 3, kg = c & 7;
      int kgs = kg ^ (row & 7);  // pre-swizzled source chunk
      const bf16* ga = A + (size_t)(m0 + row) * lda + k0 + kgs * 8;
      gload_lds16(ga, &Asm[(p * 256 + w * 64) * 8]);
      const bf16* gb = Bw + (size_t)(n0 + row) * ldb + k0 + kgs * 8;
      gload_lds16(gb, &Bsm[(p * 256 + w * 64) * 8]);
    }
    __syncthreads();
#pragma unroll
    for (int kk = 0; kk < 2; kk++) {
      bf16x8 am[4], bn[4];
#pragma unroll
      for (int i = 0; i < 4; i++) {
        int ra = wr * 64 + i * 16 + l15;
        am[i] = *(const bf16x8*)&Asm[ra * 64 + ((kk * 32 + l4 * 8) ^ ((ra & 7) * 8))];
        int rb = wc * 64 + i * 16 + l15;
        bn[i] = *(const bf16x8*)&Bsm[rb * 64 + ((kk * 32 + l4 * 8) ^ ((rb & 7) * 8))];
      }
#pragma unroll
      for (int i = 0; i < 4; i++)
#pragma unroll
        for (int j = 0; j < 4; j++)
          acc[i][j] = __builtin_amdgcn_mfma_f32_16x16x32_bf16(am[i], bn[j], acc[i][j], 0, 0, 0);
    }
    __syncthreads();
  }

  if (OUTMODE == 1) {
#pragma unroll
    for (int i = 0; i < 4; i++)
#pragma unroll
      for (int j = 0; j < 4; j++)
#pragma unroll
        for (int r = 0; r < 4; r++) {
          int m = m0 + wr * 64 + i * 16 + l4 * 4 + r;
          int n = n0 + wc * 64 + j * 16 + l15;
          ((float*)Cv)[(size_t)m * ldc + n] = acc[i][j][r] + bias[n];
        }
  } else {
    int btype = n0 >> 10;                     // 0=Q, 1=K, 2=V
    int h = ((n0 & 1023) >> 6) + wc;          // head index
    if (btype < 2) {
      const float2* tab = (btype == 0) ? qtab : ktab;
#pragma unroll
      for (int i = 0; i < 4; i++) {
        int mbase = m0 + wr * 64 + i * 16 + l4 * 4;
#pragma unroll
        for (int r = 0; r < 4; r++) {
          int m = mbase + r;
          int s = m & 2047, b = m >> 11;
#pragma unroll
          for (int j = 0; j < 2; j++) {
            int d1 = j * 16 + l15;
            float2 cs = tab[s * 32 + d1];
            float t1 = acc[i][j][r], t2 = acc[i][j + 2][r];
            bf16 o1 = __float2bfloat16(t1 * cs.x - t2 * cs.y);
            bf16 o2 = __float2bfloat16(t1 * cs.y + t2 * cs.x);
            if (btype == 0) {
              bf16* dst = qh + ((size_t)(b * H_ + h) * S_ + s) * D_;
              dst[d1] = o1;
              dst[d1 + 32] = o2;
            } else {
              int row = s & 63, kt = s >> 6, sz = (row & 7) * 8;
              bf16* dst = khsw + (((size_t)(b * H_ + h) * 32 + kt) * 64 + row) * 64;
              dst[d1 ^ sz] = o1;
              dst[(d1 + 32) ^ sz] = o2;
            }
          }
        }
      }
    } else {
#pragma unroll
      for (int i = 0; i < 4; i++) {
        int mbase = m0 + wr * 64 + i * 16 + l4 * 4;
        int c0 = mbase & 63, kt = (mbase >> 6) & 31, b = mbase >> 11;
#pragma unroll
        for (int j = 0; j < 4; j++) {
          int d = j * 16 + l15;
          union { bf16x4 v; short e[4]; } pk;
#pragma unroll
          for (int r = 0; r < 4; r++) {
            bf16 tv = __float2bfloat16(acc[i][j][r]);
            pk.e[r] = *(short*)&tv;
          }
          *(bf16x4*)&vtsw[(((size_t)(b * H_ + h) * 32 + kt) * 64 + d) * 64 +
                          (c0 ^ ((d & 7) * 8))] = pk.v;
        }
      }
    }
  }
}

// ---------- Flash attention: S^T QK (lane-local softmax) + K=32 PV ----------
__launch_bounds__(256, 3)
__global__ void attn_kernel(const bf16* __restrict__ qh, const bf16* __restrict__ khsw,
                            const bf16* __restrict__ vtsw, bf16* __restrict__ attn) {
  __shared__ bf16 Ksm[2][4096];
  __shared__ bf16 Vsm[2][4096];
  __shared__ bf16 Plds[4][2][16][72];
  int t = threadIdx.x, lane = t & 63, w = t >> 6;
  int l15 = lane & 15, l4 = lane >> 4;
  int swz = (l15 & 7) * 8;
  int st = 15 - (blockIdx.x >> 6);   // heavy strips dispatched first
  int bh = blockIdx.x & 63;
  int b = bh >> 4, h = bh & 15;
  const bf16* Qh = qh + (size_t)bh * S_ * D_;

#define STAGE(bb, kt)                                                          \
  do {                                                                         \
    const bf16* kb_ = khsw + ((size_t)bh * 32 + (kt)) * 4096 + w * 1024 + lane * 8; \
    const bf16* vb_ = vtsw + ((size_t)bh * 32 + (kt)) * 4096 + w * 1024 + lane * 8; \
    gload_lds16(kb_, &Ksm[bb][w * 1024]);                                      \
    gload_lds16(kb_ + 512, &Ksm[bb][w * 1024 + 512]);                          \
    gload_lds16(vb_, &Vsm[bb][w * 1024]);                                      \
    gload_lds16(vb_ + 512, &Vsm[bb][w * 1024 + 512]);                          \
  } while (0)

  int q0 = st * 128 + w * 32;
  int nt = 2 * st + 2;

  bf16x8 qf[2][2];
#pragma unroll
  for (int qg = 0; qg < 2; qg++)
#pragma unroll
    for (int sl = 0; sl < 2; sl++)
      qf[qg][sl] = *(const bf16x8*)&Qh[(size_t)(q0 + qg * 16 + l15) * D_ + sl * 32 + l4 * 8];

  f32x4 acc_o[2][4];
  float lsum[2] = {0.f, 0.f};
#pragma unroll
  for (int qg = 0; qg < 2; qg++)
#pragma unroll
    for (int j = 0; j < 4; j++) acc_o[qg][j] = (f32x4){0.f, 0.f, 0.f, 0.f};

  STAGE(0, 0);
  __syncthreads();
  int buf = 0;
  for (int ti = 0; ti < nt; ti++) {
    int kb = ti * 64;
    if (ti + 1 < nt) STAGE(buf ^ 1, ti + 1);
    if (kb <= q0 + 31) {
      bool maskt = (kb + 63 > q0);
      f32x4 s[2][4];
      __builtin_amdgcn_s_setprio(1);
#pragma unroll
      for (int cb = 0; cb < 4; cb++) {
        bf16x8 kf0 = *(const bf16x8*)&Ksm[buf][(cb * 16 + l15) * 64 + ((l4 * 8) ^ swz)];
        bf16x8 kf1 = *(const bf16x8*)&Ksm[buf][(cb * 16 + l15) * 64 + ((32 + l4 * 8) ^ swz)];
#pragma unroll
        for (int qg = 0; qg < 2; qg++) {
          f32x4 z = (f32x4){0.f, 0.f, 0.f, 0.f};
          z = __builtin_amdgcn_mfma_f32_16x16x32_bf16(kf0, qf[qg][0], z, 0, 0, 0);
          z = __builtin_amdgcn_mfma_f32_16x16x32_bf16(kf1, qf[qg][1], z, 0, 0, 0);
          s[qg][cb] = z;
        }
      }
      __builtin_amdgcn_s_setprio(0);
#pragma unroll
      for (int qg = 0; qg < 2; qg++) {
        int q = q0 + qg * 16 + l15;
#pragma unroll
        for (int cb = 0; cb < 4; cb++) {
          union { bf16x4 v; short e[4]; } pk;
#pragma unroll
          for (int r = 0; r < 4; r++) {
            float p = exp2f(s[qg][cb][r]);
            if (maskt && (kb + cb * 16 + l4 * 4 + r > q)) p = 0.f;
            lsum[qg] += p;
            bf16 pb16 = __float2bfloat16(p);
            pk.e[r] = *(short*)&pb16;
          }
          *(bf16x4*)&Plds[w][qg][l15][cb * 16 + l4 * 4] = pk.v;
        }
      }
      __builtin_amdgcn_s_setprio(1);
#pragma unroll
      for (int qg = 0; qg < 2; qg++) {
        bf16x8 pf0 = *(const bf16x8*)&Plds[w][qg][l15][l4 * 8];
        bf16x8 pf1 = *(const bf16x8*)&Plds[w][qg][l15][32 + l4 * 8];
#pragma unroll
        for (int db = 0; db < 4; db++) {
          bf16x8 vf0 = *(const bf16x8*)&Vsm[buf][(db * 16 + l15) * 64 + ((l4 * 8) ^ swz)];
          bf16x8 vf1 = *(const bf16x8*)&Vsm[buf][(db * 16 + l15) * 64 + ((32 + l4 * 8) ^ swz)];
          acc_o[qg][db] = __builtin_amdgcn_mfma_f32_16x16x32_bf16(pf0, vf0, acc_o[qg][db], 0, 0, 0);
          acc_o[qg][db] = __builtin_amdgcn_mfma_f32_16x16x32_bf16(pf1, vf1, acc_o[qg][db], 0, 0, 0);
        }
      }
      __builtin_amdgcn_s_setprio(0);
    }
    __syncthreads();
    buf ^= 1;
  }

  float invr[2][4];
#pragma unroll
  for (int qg = 0; qg < 2; qg++) {
    float ls = lsum[qg];
    ls += __shfl_xor(ls, 16, 64);
    ls += __shfl_xor(ls, 32, 64);
    float inv = 1.0f / ls;
#pragma unroll
    for (int r = 0; r < 4; r++) invr[qg][r] = __shfl(inv, l4 * 4 + r, 64);
  }

#pragma unroll
  for (int qg = 0; qg < 2; qg++)
#pragma unroll
    for (int db = 0; db < 4; db++)
#pragma unroll
      for (int r = 0; r < 4; r++) {
        int qa = q0 + qg * 16 + l4 * 4 + r;
        attn[(size_t)(b * S_ + qa) * E_ + h * 64 + db * 16 + l15] =
            __float2bfloat16(acc_o[qg][db][r] * invr[qg][r]);
      }
#undef STAGE
}

extern "C" void kernel_launch(void* const* d_in, const int* in_sizes, int n_in,
                              void* d_out, int out_size, void* d_ws, size_t ws_size,
                              hipStream_t stream) {
  const float* x  = (const float*)d_in[0];
  const float* Wq = (const float*)d_in[1];
  const float* Wk = (const float*)d_in[2];
  const float* Wv = (const float*)d_in[3];
  const float* Wp = (const float*)d_in[4];
  const float* bp = (const float*)d_in[5];

  char* ws = (char*)d_ws;
  bf16* x_bf   = (bf16*)(ws + 0);                     // 16 MB
  bf16* w_bf   = (bf16*)(ws + (16u << 20));           //  8 MB (Wq|Wk|Wv|Wp)
  bf16* aout   = (bf16*)(ws + (24u << 20));           // 16 MB
  bf16* qh     = (bf16*)(ws + (40u << 20));           // 16 MB
  bf16* khsw   = (bf16*)(ws + (56u << 20));           // 16 MB (swizzled tiles)
  bf16* vtsw   = (bf16*)(ws + (72u << 20));           // 16 MB (swizzled tiles)
  float2* qtab = (float2*)(ws + (88u << 20));         // 512 KB
  float2* ktab = (float2*)(ws + (88u << 20) + (512u << 10));  // 512 KB

  prep_kernel<<<6400, 256, 0, stream>>>(x, Wq, Wk, Wv, Wp, x_bf, w_bf, qtab, ktab);

  gemm_bt_kernel<2><<<(M_ / 128) * (NQKV / 128), 256, 0, stream>>>(
      x_bf, E_, w_bf, E_, nullptr, 0, nullptr, E_, NQKV / 128,
      qtab, ktab, qh, khsw, vtsw);

  attn_kernel<<<16 * 64, 256, 0, stream>>>(qh, khsw, vtsw, aout);

  gemm_bt_kernel<1><<<(M_ / 128) * (E_ / 128), 256, 0, stream>>>(
      aout, E_, w_bf + 3 * (size_t)E_ * E_, E_, d_out, E_, bp, E_, E_ / 128,
      nullptr, nullptr, nullptr, nullptr, nullptr);
}

// Round 11
// 169.471 us; speedup vs baseline: 1.2500x; 1.0396x over previous
//
#include <hip/hip_runtime.h>
#include <hip/hip_bf16.h>

typedef __hip_bfloat16 bf16;
typedef __attribute__((ext_vector_type(8))) short bf16x8;
typedef __attribute__((ext_vector_type(4))) short bf16x4;
typedef __attribute__((ext_vector_type(4))) float f32x4;

static constexpr int B_ = 4, S_ = 2048, E_ = 1024, H_ = 16, D_ = 64;
static constexpr int M_ = B_ * S_;   // 8192
static constexpr int NQKV = 3 * E_;  // 3072

__device__ __forceinline__ void gload_lds16(const void* g, void* l) {
  __builtin_amdgcn_global_load_lds(
      (const __attribute__((address_space(1))) unsigned int*)g,
      (__attribute__((address_space(3))) unsigned int*)l, 16, 0, 0);
}

__device__ __forceinline__ void cast8(const float* __restrict__ src,
                                      bf16* __restrict__ dst, int t) {
  float4 a = ((const float4*)src)[2 * t];
  float4 b = ((const float4*)src)[2 * t + 1];
  union { bf16x8 v; bf16 e[8]; } u;
  u.e[0] = __float2bfloat16(a.x); u.e[1] = __float2bfloat16(a.y);
  u.e[2] = __float2bfloat16(a.z); u.e[3] = __float2bfloat16(a.w);
  u.e[4] = __float2bfloat16(b.x); u.e[5] = __float2bfloat16(b.y);
  u.e[6] = __float2bfloat16(b.z); u.e[7] = __float2bfloat16(b.w);
  ((bf16x8*)dst)[t] = u.v;
}

// ---------- fused prologue: casts + rope tables, one launch ----------
__global__ void prep_kernel(const float* __restrict__ x, const float* __restrict__ Wq,
                            const float* __restrict__ Wk, const float* __restrict__ Wv,
                            const float* __restrict__ Wp,
                            bf16* __restrict__ x_bf, bf16* __restrict__ w_bf,
                            float2* __restrict__ qtab, float2* __restrict__ ktab) {
  int bid = blockIdx.x;
  if (bid < 4096) {
    cast8(x, x_bf, bid * 256 + threadIdx.x);
  } else if (bid < 6144) {
    int wi = (bid - 4096) >> 9;
    const float* src = wi == 0 ? Wq : wi == 1 ? Wk : wi == 2 ? Wv : Wp;
    cast8(src, w_bf + (size_t)wi * E_ * E_, ((bid - 4096) & 511) * 256 + threadIdx.x);
  } else {
    int tt = (bid - 6144) * 256 + threadIdx.x;  // < S_*32
    int i = tt & 31, s = tt >> 5;
    float inv_freq = powf(10000.0f, -(float)i / 32.0f);
    float ang = (float)s * inv_freq;
    float c = cosf(ang), sn = sinf(ang);
    const float qsc = 0.18033688011112043f;  // 1/8 * log2(e)
    qtab[tt] = make_float2(c * qsc, sn * qsc);
    ktab[tt] = make_float2(c, sn);
  }
}

// ---------- GEMM: C[m][n] = sum_k A[m][k] * Bw[n][k], BM x 128 tile, BK=64 ----------
// R6-proven loop (single-buffered LDS, stage -> barrier(drain) -> compute ->
// barrier), source-side XOR chunk swizzle -> conflict-free ds_read_b128,
// XCD-aware bijective block swizzle. BM=256 (8 waves) for QKV: stages 25%
// fewer bytes per FLOP than 128^2 (L2-staging-bound theory). BM=128 for proj
// (grid stays 512 = 2/CU, no idle CUs).
// OUTMODE 1: f32 out + bias (proj). OUTMODE 2: fused QKV rope/layout epilogue.
template <int OUTMODE, int BM>
__launch_bounds__(BM * 2)
__global__ void gemm_bt_kernel(const bf16* __restrict__ A, int lda,
                               const bf16* __restrict__ Bw, int ldb,
                               void* __restrict__ Cv, int ldc,
                               const float* __restrict__ bias,
                               int K, int ntiles_n,
                               const float2* __restrict__ qtab,
                               const float2* __restrict__ ktab,
                               bf16* __restrict__ qh,
                               bf16* __restrict__ khsw,
                               bf16* __restrict__ vtsw) {
  constexpr int NTHR = BM * 2;
  __shared__ bf16 Asm[BM * 64];
  __shared__ bf16 Bsm[128 * 64];
  int t = threadIdx.x;
  int lane = t & 63, wid = t >> 6;
  int wm = wid >> 1, wc = wid & 1;
  int l15 = lane & 15, l4 = lane >> 4;

  // XCD-aware bijective swizzle; gridDim.x is a multiple of 8.
  int cpx = gridDim.x >> 3;
  int swb = (blockIdx.x & 7) * cpx + (blockIdx.x >> 3);
  int n0 = (swb % ntiles_n) * 128;
  int m0 = (swb / ntiles_n) * BM;

  f32x4 acc[4][4];
#pragma unroll
  for (int i = 0; i < 4; i++)
#pragma unroll
    for (int j = 0; j < 4; j++) acc[i][j] = (f32x4){0.f, 0.f, 0.f, 0.f};

  for (int k0 = 0; k0 < K; k0 += 64) {
    // stage A: BM*8 chunks, 4 per thread
#pragma unroll
    for (int p = 0; p < 4; p++) {
      int c = p * NTHR + t;
      int row = c >> 3, kg = c & 7;
      int kgs = kg ^ (row & 7);  // pre-swizzled source chunk
      gload_lds16(A + (size_t)(m0 + row) * lda + k0 + kgs * 8, &Asm[c * 8]);
    }
    // stage B: 1024 chunks, 1024/NTHR per thread
#pragma unroll
    for (int p = 0; p < 1024 / NTHR; p++) {
      int c = p * NTHR + t;
      int row = c >> 3, kg = c & 7;
      int kgs = kg ^ (row & 7);
      gload_lds16(Bw + (size_t)(n0 + row) * ldb + k0 + kgs * 8, &Bsm[c * 8]);
    }
    __syncthreads();
#pragma unroll
    for (int kk = 0; kk < 2; kk++) {
      bf16x8 am[4], bn[4];
#pragma unroll
      for (int i = 0; i < 4; i++) {
        int ra = wm * 64 + i * 16 + l15;
        am[i] = *(const bf16x8*)&Asm[ra * 64 + ((kk * 32 + l4 * 8) ^ ((ra & 7) * 8))];
        int rb = wc * 64 + i * 16 + l15;
        bn[i] = *(const bf16x8*)&Bsm[rb * 64 + ((kk * 32 + l4 * 8) ^ ((rb & 7) * 8))];
      }
#pragma unroll
      for (int i = 0; i < 4; i++)
#pragma unroll
        for (int j = 0; j < 4; j++)
          acc[i][j] = __builtin_amdgcn_mfma_f32_16x16x32_bf16(am[i], bn[j], acc[i][j], 0, 0, 0);
    }
    __syncthreads();
  }

  if (OUTMODE == 1) {
#pragma unroll
    for (int i = 0; i < 4; i++)
#pragma unroll
      for (int j = 0; j < 4; j++)
#pragma unroll
        for (int r = 0; r < 4; r++) {
          int m = m0 + wm * 64 + i * 16 + l4 * 4 + r;
          int n = n0 + wc * 64 + j * 16 + l15;
          ((float*)Cv)[(size_t)m * ldc + n] = acc[i][j][r] + bias[n];
        }
  } else {
    int btype = n0 >> 10;                     // 0=Q, 1=K, 2=V
    int h = ((n0 & 1023) >> 6) + wc;          // head index
    if (btype < 2) {
      const float2* tab = (btype == 0) ? qtab : ktab;
#pragma unroll
      for (int i = 0; i < 4; i++) {
        int mbase = m0 + wm * 64 + i * 16 + l4 * 4;
#pragma unroll
        for (int r = 0; r < 4; r++) {
          int m = mbase + r;
          int s = m & 2047, b = m >> 11;
#pragma unroll
          for (int j = 0; j < 2; j++) {
            int d1 = j * 16 + l15;
            float2 cs = tab[s * 32 + d1];
            float t1 = acc[i][j][r], t2 = acc[i][j + 2][r];
            bf16 o1 = __float2bfloat16(t1 * cs.x - t2 * cs.y);
            bf16 o2 = __float2bfloat16(t1 * cs.y + t2 * cs.x);
            if (btype == 0) {
              bf16* dst = qh + ((size_t)(b * H_ + h) * S_ + s) * D_;
              dst[d1] = o1;
              dst[d1 + 32] = o2;
            } else {
              int row = s & 63, kt = s >> 6, sz = (row & 7) * 8;
              bf16* dst = khsw + (((size_t)(b * H_ + h) * 32 + kt) * 64 + row) * 64;
              dst[d1 ^ sz] = o1;
              dst[(d1 + 32) ^ sz] = o2;
            }
          }
        }
      }
    } else {
#pragma unroll
      for (int i = 0; i < 4; i++) {
        int mbase = m0 + wm * 64 + i * 16 + l4 * 4;
        int c0 = mbase & 63, kt = (mbase >> 6) & 31, b = mbase >> 11;
#pragma unroll
        for (int j = 0; j < 4; j++) {
          int d = j * 16 + l15;
          union { bf16x4 v; short e[4]; } pk;
#pragma unroll
          for (int r = 0; r < 4; r++) {
            bf16 tv = __float2bfloat16(acc[i][j][r]);
            pk.e[r] = *(short*)&tv;
          }
          *(bf16x4*)&vtsw[(((size_t)(b * H_ + h) * 32 + kt) * 64 + d) * 64 +
                          (c0 ^ ((d & 7) * 8))] = pk.v;
        }
      }
    }
  }
}

// ---------- Flash attention: S^T QK (lane-local softmax) + K=32 PV ----------
__launch_bounds__(256, 3)
__global__ void attn_kernel(const bf16* __restrict__ qh, const bf16* __restrict__ khsw,
                            const bf16* __restrict__ vtsw, bf16* __restrict__ attn) {
  __shared__ bf16 Ksm[2][4096];
  __shared__ bf16 Vsm[2][4096];
  __shared__ bf16 Plds[4][2][16][72];
  int t = threadIdx.x, lane = t & 63, w = t >> 6;
  int l15 = lane & 15, l4 = lane >> 4;
  int swz = (l15 & 7) * 8;
  int st = 15 - (blockIdx.x >> 6);   // heavy strips dispatched first
  int bh = blockIdx.x & 63;
  int b = bh >> 4, h = bh & 15;
  const bf16* Qh = qh + (size_t)bh * S_ * D_;

#define STAGE(bb, kt)                                                          \
  do {                                                                         \
    const bf16* kb_ = khsw + ((size_t)bh * 32 + (kt)) * 4096 + w * 1024 + lane * 8; \
    const bf16* vb_ = vtsw + ((size_t)bh * 32 + (kt)) * 4096 + w * 1024 + lane * 8; \
    gload_lds16(kb_, &Ksm[bb][w * 1024]);                                      \
    gload_lds16(kb_ + 512, &Ksm[bb][w * 1024 + 512]);                          \
    gload_lds16(vb_, &Vsm[bb][w * 1024]);                                      \
    gload_lds16(vb_ + 512, &Vsm[bb][w * 1024 + 512]);                          \
  } while (0)

  int q0 = st * 128 + w * 32;
  int nt = 2 * st + 2;

  bf16x8 qf[2][2];
#pragma unroll
  for (int qg = 0; qg < 2; qg++)
#pragma unroll
    for (int sl = 0; sl < 2; sl++)
      qf[qg][sl] = *(const bf16x8*)&Qh[(size_t)(q0 + qg * 16 + l15) * D_ + sl * 32 + l4 * 8];

  f32x4 acc_o[2][4];
  float lsum[2] = {0.f, 0.f};
#pragma unroll
  for (int qg = 0; qg < 2; qg++)
#pragma unroll
    for (int j = 0; j < 4; j++) acc_o[qg][j] = (f32x4){0.f, 0.f, 0.f, 0.f};

  STAGE(0, 0);
  __syncthreads();
  int buf = 0;
  for (int ti = 0; ti < nt; ti++) {
    int kb = ti * 64;
    if (ti + 1 < nt) STAGE(buf ^ 1, ti + 1);
    if (kb <= q0 + 31) {
      bool maskt = (kb + 63 > q0);
      f32x4 s[2][4];
      __builtin_amdgcn_s_setprio(1);
#pragma unroll
      for (int cb = 0; cb < 4; cb++) {
        bf16x8 kf0 = *(const bf16x8*)&Ksm[buf][(cb * 16 + l15) * 64 + ((l4 * 8) ^ swz)];
        bf16x8 kf1 = *(const bf16x8*)&Ksm[buf][(cb * 16 + l15) * 64 + ((32 + l4 * 8) ^ swz)];
#pragma unroll
        for (int qg = 0; qg < 2; qg++) {
          f32x4 z = (f32x4){0.f, 0.f, 0.f, 0.f};
          z = __builtin_amdgcn_mfma_f32_16x16x32_bf16(kf0, qf[qg][0], z, 0, 0, 0);
          z = __builtin_amdgcn_mfma_f32_16x16x32_bf16(kf1, qf[qg][1], z, 0, 0, 0);
          s[qg][cb] = z;
        }
      }
      __builtin_amdgcn_s_setprio(0);
#pragma unroll
      for (int qg = 0; qg < 2; qg++) {
        int q = q0 + qg * 16 + l15;
#pragma unroll
        for (int cb = 0; cb < 4; cb++) {
          union { bf16x4 v; short e[4]; } pk;
#pragma unroll
          for (int r = 0; r < 4; r++) {
            float p = exp2f(s[qg][cb][r]);
            if (maskt && (kb + cb * 16 + l4 * 4 + r > q)) p = 0.f;
            lsum[qg] += p;
            bf16 pb16 = __float2bfloat16(p);
            pk.e[r] = *(short*)&pb16;
          }
          *(bf16x4*)&Plds[w][qg][l15][cb * 16 + l4 * 4] = pk.v;
        }
      }
      __builtin_amdgcn_s_setprio(1);
#pragma unroll
      for (int qg = 0; qg < 2; qg++) {
        bf16x8 pf0 = *(const bf16x8*)&Plds[w][qg][l15][l4 * 8];
        bf16x8 pf1 = *(const bf16x8*)&Plds[w][qg][l15][32 + l4 * 8];
#pragma unroll
        for (int db = 0; db < 4; db++) {
          bf16x8 vf0 = *(const bf16x8*)&Vsm[buf][(db * 16 + l15) * 64 + ((l4 * 8) ^ swz)];
          bf16x8 vf1 = *(const bf16x8*)&Vsm[buf][(db * 16 + l15) * 64 + ((32 + l4 * 8) ^ swz)];
          acc_o[qg][db] = __builtin_amdgcn_mfma_f32_16x16x32_bf16(pf0, vf0, acc_o[qg][db], 0, 0, 0);
          acc_o[qg][db] = __builtin_amdgcn_mfma_f32_16x16x32_bf16(pf1, vf1, acc_o[qg][db], 0, 0, 0);
        }
      }
      __builtin_amdgcn_s_setprio(0);
    }
    __syncthreads();
    buf ^= 1;
  }

  float invr[2][4];
#pragma unroll
  for (int qg = 0; qg < 2; qg++) {
    float ls = lsum[qg];
    ls += __shfl_xor(ls, 16, 64);
    ls += __shfl_xor(ls, 32, 64);
    float inv = 1.0f / ls;
#pragma unroll
    for (int r = 0; r < 4; r++) invr[qg][r] = __shfl(inv, l4 * 4 + r, 64);
  }

#pragma unroll
  for (int qg = 0; qg < 2; qg++)
#pragma unroll
    for (int db = 0; db < 4; db++)
#pragma unroll
      for (int r = 0; r < 4; r++) {
        int qa = q0 + qg * 16 + l4 * 4 + r;
        attn[(size_t)(b * S_ + qa) * E_ + h * 64 + db * 16 + l15] =
            __float2bfloat16(acc_o[qg][db][r] * invr[qg][r]);
      }
#undef STAGE
}

extern "C" void kernel_launch(void* const* d_in, const int* in_sizes, int n_in,
                              void* d_out, int out_size, void* d_ws, size_t ws_size,
                              hipStream_t stream) {
  const float* x  = (const float*)d_in[0];
  const float* Wq = (const float*)d_in[1];
  const float* Wk = (const float*)d_in[2];
  const float* Wv = (const float*)d_in[3];
  const float* Wp = (const float*)d_in[4];
  const float* bp = (const float*)d_in[5];

  char* ws = (char*)d_ws;
  bf16* x_bf   = (bf16*)(ws + 0);                     // 16 MB
  bf16* w_bf   = (bf16*)(ws + (16u << 20));           //  8 MB (Wq|Wk|Wv|Wp)
  bf16* aout   = (bf16*)(ws + (24u << 20));           // 16 MB
  bf16* qh     = (bf16*)(ws + (40u << 20));           // 16 MB
  bf16* khsw   = (bf16*)(ws + (56u << 20));           // 16 MB (swizzled tiles)
  bf16* vtsw   = (bf16*)(ws + (72u << 20));           // 16 MB (swizzled tiles)
  float2* qtab = (float2*)(ws + (88u << 20));         // 512 KB
  float2* ktab = (float2*)(ws + (88u << 20) + (512u << 10));  // 512 KB

  prep_kernel<<<6400, 256, 0, stream>>>(x, Wq, Wk, Wv, Wp, x_bf, w_bf, qtab, ktab);

  // fused QKV projection + rope + layout: 256x128 tiles -> 32*24 = 768 blocks
  gemm_bt_kernel<2, 256><<<(M_ / 256) * (NQKV / 128), 512, 0, stream>>>(
      x_bf, E_, w_bf, E_, nullptr, 0, nullptr, E_, NQKV / 128,
      qtab, ktab, qh, khsw, vtsw);

  attn_kernel<<<16 * 64, 256, 0, stream>>>(qh, khsw, vtsw, aout);

  // output projection: 128x128 tiles -> 64*8 = 512 blocks (2/CU, no idle)
  gemm_bt_kernel<1, 128><<<(M_ / 128) * (E_ / 128), 256, 0, stream>>>(
      aout, E_, w_bf + 3 * (size_t)E_ * E_, E_, d_out, E_, bp, E_, E_ / 128,
      nullptr, nullptr, nullptr, nullptr, nullptr);
}